// Round 7
// baseline (166.582 us; speedup 1.0000x reference)
//
#include <hip/hip_runtime.h>
#include <hip/hip_bf16.h>

// DCNv2: B=4, C=64, H=W=128, O=64, KS=3, N=9, PAD=1. I/O float32.
#define BB 4
#define CC 64
#define HH 128
#define WW 128
#define OO 64
#define NN 9
#define HW 16384
#define HP 130
#define WP 130

// ---- ws layout (float-slot offsets) ----
// 0        wpmb bf16 [32][576]   (rows 0..17 w_p, 18..26 w_m, 27..31 zero)
// 9216     bias fp32 (18 b_p then 9 b_m)
// 9248     wcb  bf16 [o(64)][K(576)], K = kt*64+c
// 27680    xt   bf16 [b][hw][c]
#define WPMB_F  0
#define BPM_OFF 9216
#define WCB_F   9248
#define XT_F    27680

typedef __attribute__((ext_vector_type(8))) short s8v;
typedef __attribute__((ext_vector_type(8))) unsigned short u8v;
typedef __attribute__((ext_vector_type(4))) float f4v;

__device__ __forceinline__ unsigned short f2bu(float f) {   // fp32 -> bf16 bits (RNE)
    unsigned int b = __float_as_uint(f);
    return (unsigned short)((b + 0x7FFFu + ((b >> 16) & 1u)) >> 16);
}
__device__ __forceinline__ float bu2f(unsigned short u) {
    return __uint_as_float(((unsigned int)u) << 16);
}

#define MF(a, bb, c) __builtin_amdgcn_mfma_f32_16x16x32_bf16(a, bb, c, 0, 0, 0)

// blocks [0,1024): NCHW fp32 -> NHWC bf16 transpose via LDS tile (XCD-swizzled
// to match k_main's consumer mapping). blocks [1024,1248): weight prep.
__global__ void __launch_bounds__(256) k_pxt(const float* __restrict__ x,
                                             const float* __restrict__ wp,
                                             const float* __restrict__ bp,
                                             const float* __restrict__ wm,
                                             const float* __restrict__ bm,
                                             const float* __restrict__ wcv,
                                             float* __restrict__ ws) {
    int blk = blockIdx.x;
    int t = threadIdx.x;
    if (blk >= 1024) {                       // ---- weight prep path ----
        int tid = (blk - 1024) * 256 + t;
        if (tid < 18432) {                   // wpmb [32][576]
            int r = tid / 576;
            int kk = tid % 576;              // kk = kt*64 + c
            int kt = kk >> 6;
            int c = kk & 63;
            int dy = kt / 3, dx = kt % 3;
            float v = 0.f;
            if (r < 18)       v = wp[((r * 64 + c) * 3 + dy) * 3 + dx];
            else if (r < 27)  v = wm[(((r - 18) * 64 + c) * 3 + dy) * 3 + dx];
            ((unsigned short*)(ws + WPMB_F))[tid] = f2bu(v);
        } else if (tid < 18459) {
            int i = tid - 18432;
            ws[BPM_OFF + i] = (i < 18) ? bp[i] : bm[i - 18];
        } else if (tid >= 20480) {           // wcb [64][576], tid < 57344 by grid
            int d = tid - 20480;
            int o = d / 576;
            int kk = d % 576;
            int kt = kk >> 6;
            int c = kk & 63;
            ((unsigned short*)(ws + WCB_F))[o * 576 + kk] = f2bu(wcv[(o * 64 + c) * 9 + kt]);
        }
        return;
    }
    // ---- transpose: block = 64 hw x 64 ch, tile stored [hw][c] ----
    __shared__ unsigned short tile[64][72];   // 16B-aligned rows (144B)
    int sb = ((blk & 7) << 7) | (blk >> 3);   // XCD-chunked bijection on [0,1024)
    int b = sb >> 8;
    int hw0 = (sb & 255) * 64;
    unsigned short* xt = (unsigned short*)(ws + XT_F);

#pragma unroll
    for (int p = 0; p < 4; p++) {            // coalesced float4 reads: 256B/instr per c-row
        int c = p * 16 + (t >> 4);
        int h4 = (t & 15) * 4;
        float4 v = *(const float4*)(x + ((size_t)(b * 64 + c)) * HW + hw0 + h4);
        tile[h4 + 0][c] = f2bu(v.x);
        tile[h4 + 1][c] = f2bu(v.y);
        tile[h4 + 2][c] = f2bu(v.z);
        tile[h4 + 3][c] = f2bu(v.w);
    }
    __syncthreads();
#pragma unroll
    for (int p = 0; p < 2; p++) {            // contiguous 16B/lane stores: 1KB/wave
        int hw = p * 32 + (t >> 3);
        int cb = (t & 7) * 8;
        u8v o = *(const u8v*)(&tile[hw][cb]);
        *(u8v*)(xt + ((size_t)(b * HW + hw0 + hw)) * 64 + cb) = o;
    }
}

// Fused offset-conv + sampler + einsum, wave-synchronous, REGISTER-DIRECT B path.
// Each lane gathers its OWN pixel (ln15) at its OWN k-slice (quad*8 / 32+quad*8),
// blends in f32, and the result IS the MFMA B-fragment — no LDS staging at all.
// Gather instrs cover 16 pixels x one aligned 64B line each (half the transactions
// of the 32ch/lane pattern). LDS = pxm buffer only. XCD swizzle keeps L2-hot.
__global__ void __launch_bounds__(256, 4) k_main(const float* __restrict__ ws,
                                                 float* __restrict__ out) {
    __shared__ float pxmL[4][3][NN][16];     // [wave][{px,py,m}][tap][pixel]

    int t = threadIdx.x;
    int lane = t & 63;
    int wv = t >> 6;
    int ln15 = lane & 15;
    int quad = lane >> 4;

    int braw = blockIdx.x;                   // 1024 = 8 XCD * 128: chunked swizzle
    int blk = ((braw & 7) << 7) | (braw >> 3);
    int b = blk >> 8;
    int hw0 = (blk & 255) * 64 + wv * 16;    // this wave's 16-pixel base

    const unsigned short* wpmb = (const unsigned short*)(ws + WPMB_F);
    const unsigned short* wcb  = (const unsigned short*)(ws + WCB_F);
    const unsigned short* xtb  = (const unsigned short*)(ws + XT_F) + (size_t)b * HW * 64;
    const float* bpm = ws + BPM_OFF;

    int gp = hw0 + ln15;                     // this lane's pixel (B-frag column)
    int ph = gp >> 7, pw = gp & 127;
    int c0 = quad * 8;                       // this lane's k-slice base (A and B)

    const s8v zs = (s8v){0, 0, 0, 0, 0, 0, 0, 0};
    const f4v zf = (f4v){0.f, 0.f, 0.f, 0.f};

    // ================= PHASE 1: offset/modulation GEMM (M=27, K=576) =================
    {
        f4v acc1[2];
        acc1[0] = zf;
        acc1[1] = zf;
        s8v b0 = zs, b1 = zs;
        {   // prologue: B(kt=0) register-direct (dy=0,dx=0)
            int h2 = ph - 1, w2 = pw - 1;
            if (((unsigned)h2 < 128u) && ((unsigned)w2 < 128u)) {
                const unsigned short* s = xtb + (size_t)(h2 * 128 + w2) * 64;
                b0 = *(const s8v*)(s + c0);
                b1 = *(const s8v*)(s + 32 + c0);
            }
        }
#pragma unroll 1
        for (int kt = 0; kt < 9; kt++) {
            // A(kt) — issued FIRST (vmcnt FIFO: MFMA's wait drains only A)
            const unsigned short* a = wpmb + ln15 * 576 + kt * 64;
            s8v a00 = *(const s8v*)(a + c0);
            s8v a01 = *(const s8v*)(a + 32 + c0);
            s8v a10 = *(const s8v*)(a + 16 * 576 + c0);
            s8v a11 = *(const s8v*)(a + 16 * 576 + 32 + c0);
            // B(kt+1) — in flight through the MFMA
            s8v nb0 = zs, nb1 = zs;
            if (kt < 8) {
                int k2 = kt + 1;
                int dy = k2 / 3, dx = k2 - dy * 3;
                int h2 = ph + dy - 1, w2 = pw + dx - 1;
                if (((unsigned)h2 < 128u) && ((unsigned)w2 < 128u)) {
                    const unsigned short* s = xtb + (size_t)(h2 * 128 + w2) * 64;
                    nb0 = *(const s8v*)(s + c0);
                    nb1 = *(const s8v*)(s + 32 + c0);
                }
            }
            acc1[0] = MF(a00, b0, acc1[0]);
            acc1[1] = MF(a10, b0, acc1[1]);
            acc1[0] = MF(a01, b1, acc1[0]);
            acc1[1] = MF(a11, b1, acc1[1]);
            b0 = nb0; b1 = nb1;
        }
        // epilogue -> per-wave LDS pxm. pixel = ln15, oc = mt*16 + quad*4 + r
#pragma unroll
        for (int mt = 0; mt < 2; mt++) {
#pragma unroll
            for (int r = 0; r < 4; r++) {
                int oc = mt * 16 + quad * 4 + r;
                if (oc < 27) {
                    float v = acc1[mt][r] + bpm[oc];
                    if (oc < 9) {
                        pxmL[wv][0][oc][ln15] = v + (float)(oc / 3 - 1) + (float)(ph + 1);
                    } else if (oc < 18) {
                        int k = oc - 9;
                        pxmL[wv][1][k][ln15] = v + (float)(k % 3 - 1) + (float)(pw + 1);
                    } else {
                        int k = oc - 18;
                        pxmL[wv][2][k][ln15] = 1.f / (1.f + __expf(-v));
                    }
                }
            }
        }
    }
    __builtin_amdgcn_wave_barrier();

    // ================= PHASE 2: sample + einsum GEMM (M=64, K=576) =================
    f4v acc[4];
#pragma unroll
    for (int mt = 0; mt < 4; mt++) acc[mt] = zf;

    auto desc = [&](int kt, float& g0, float& g1, float& g2, float& g3,
                    const unsigned short*& q0, const unsigned short*& q1,
                    const unsigned short*& q2, const unsigned short*& q3) {
        float px = pxmL[wv][0][kt][ln15];
        float py = pxmL[wv][1][kt][ln15];
        float mk = pxmL[wv][2][kt][ln15];
        float fx = floorf(px), fy = floorf(py);
        float pxc = fminf(fmaxf(px, 0.f), (float)(HP - 1));
        float pyc = fminf(fmaxf(py, 0.f), (float)(WP - 1));
        int qltx = (int)fminf(fmaxf(fx, 0.f), (float)(HP - 1));
        int qlty = (int)fminf(fmaxf(fy, 0.f), (float)(WP - 1));
        int qrbx = (int)fminf(fmaxf(fx + 1.f, 0.f), (float)(HP - 1));
        int qrby = (int)fminf(fmaxf(fy + 1.f, 0.f), (float)(WP - 1));

        float gltx = 1.f + ((float)qltx - pxc);
        float glty = 1.f + ((float)qlty - pyc);
        float grbx = 1.f - ((float)qrbx - pxc);
        float grby = 1.f - ((float)qrby - pyc);

        bool vlx = (qltx >= 1) && (qltx <= HH);
        bool vly = (qlty >= 1) && (qlty <= WW);
        bool vrx = (qrbx >= 1) && (qrbx <= HH);
        bool vry = (qrby >= 1) && (qrby <= WW);
        g0 = (vlx && vly) ? gltx * glty * mk : 0.f;
        g1 = (vrx && vry) ? grbx * grby * mk : 0.f;
        g2 = (vlx && vry) ? gltx * grby * mk : 0.f;
        g3 = (vrx && vly) ? grbx * glty * mk : 0.f;

        int xlt = min(max(qltx - 1, 0), HH - 1);
        int ylt = min(max(qlty - 1, 0), WW - 1);
        int xrb = min(max(qrbx - 1, 0), HH - 1);
        int yrb = min(max(qrby - 1, 0), WW - 1);
        q0 = xtb + (size_t)(xlt * WW + ylt) * 64;
        q1 = xtb + (size_t)(xrb * WW + yrb) * 64;
        q2 = xtb + (size_t)(xlt * WW + yrb) * 64;
        q3 = xtb + (size_t)(xrb * WW + ylt) * 64;
    };

    // corner loads for the next tap (in-flight registers)
    u8v e00, e01, e10, e11, e20, e21, e30, e31;   // eC0 = ch[c0..c0+8), eC1 = ch[32+c0..+8)
    float gc0, gc1, gc2, gc3;
    s8v bf0, bf1;                                  // current B-fragment (blended)

    auto blend = [&]() {
        s8v r0, r1;
#pragma unroll
        for (int j = 0; j < 8; j++) {
            float va = gc0 * bu2f(e00[j]) + gc1 * bu2f(e10[j])
                     + gc2 * bu2f(e20[j]) + gc3 * bu2f(e30[j]);
            float vb = gc0 * bu2f(e01[j]) + gc1 * bu2f(e11[j])
                     + gc2 * bu2f(e21[j]) + gc3 * bu2f(e31[j]);
            r0[j] = (short)f2bu(va);
            r1[j] = (short)f2bu(vb);
        }
        bf0 = r0; bf1 = r1;
    };

    {   // prologue: gathers(0) + blend -> bf(0)
        const unsigned short *q0, *q1, *q2, *q3;
        desc(0, gc0, gc1, gc2, gc3, q0, q1, q2, q3);
        e00 = *(const u8v*)(q0 + c0); e01 = *(const u8v*)(q0 + 32 + c0);
        e10 = *(const u8v*)(q1 + c0); e11 = *(const u8v*)(q1 + 32 + c0);
        e20 = *(const u8v*)(q2 + c0); e21 = *(const u8v*)(q2 + 32 + c0);
        e30 = *(const u8v*)(q3 + c0); e31 = *(const u8v*)(q3 + 32 + c0);
        blend();
    }

#pragma unroll 1
    for (int kt = 0; kt < 9; kt++) {
        // A(kt) — issued FIRST so the MFMA's vmcnt wait drains only A
        const unsigned short* a = wcb + ln15 * 576 + kt * 64;
        s8v a0k0 = *(const s8v*)(a + c0);
        s8v a0k1 = *(const s8v*)(a + 32 + c0);
        s8v a1k0 = *(const s8v*)(a + 16 * 576 + c0);
        s8v a1k1 = *(const s8v*)(a + 16 * 576 + 32 + c0);
        s8v a2k0 = *(const s8v*)(a + 32 * 576 + c0);
        s8v a2k1 = *(const s8v*)(a + 32 * 576 + 32 + c0);
        s8v a3k0 = *(const s8v*)(a + 48 * 576 + c0);
        s8v a3k1 = *(const s8v*)(a + 48 * 576 + 32 + c0);
        // gathers(kt+1) — stay in flight through the MFMA phase
        float ng0 = 0.f, ng1 = 0.f, ng2 = 0.f, ng3 = 0.f;
        if (kt < 8) {
            const unsigned short *q0, *q1, *q2, *q3;
            desc(kt + 1, ng0, ng1, ng2, ng3, q0, q1, q2, q3);
            e00 = *(const u8v*)(q0 + c0); e01 = *(const u8v*)(q0 + 32 + c0);
            e10 = *(const u8v*)(q1 + c0); e11 = *(const u8v*)(q1 + 32 + c0);
            e20 = *(const u8v*)(q2 + c0); e21 = *(const u8v*)(q2 + 32 + c0);
            e30 = *(const u8v*)(q3 + c0); e31 = *(const u8v*)(q3 + 32 + c0);
        }
        // MFMA(kt): B from registers (bf0/bf1 blended last iteration)
        acc[0] = MF(a0k0, bf0, acc[0]);
        acc[1] = MF(a1k0, bf0, acc[1]);
        acc[2] = MF(a2k0, bf0, acc[2]);
        acc[3] = MF(a3k0, bf0, acc[3]);
        acc[0] = MF(a0k1, bf1, acc[0]);
        acc[1] = MF(a1k1, bf1, acc[1]);
        acc[2] = MF(a2k1, bf1, acc[2]);
        acc[3] = MF(a3k1, bf1, acc[3]);
        // blend(kt+1) -> bf regs for next iteration
        if (kt < 8) {
            gc0 = ng0; gc1 = ng1; gc2 = ng2; gc3 = ng3;
            blend();
        }
    }

    // epilogue: D col = pixel, row = oc
    int pix = hw0 + ln15;
    float* ob = out + (size_t)b * (OO * HW) + pix;
#pragma unroll
    for (int mt = 0; mt < 4; mt++) {
#pragma unroll
        for (int r = 0; r < 4; r++) {
            ob[(size_t)(mt * 16 + quad * 4 + r) * HW] = acc[mt][r];
        }
    }
}

extern "C" void kernel_launch(void* const* d_in, const int* in_sizes, int n_in,
                              void* d_out, int out_size, void* d_ws, size_t ws_size,
                              hipStream_t stream) {
    const float* x   = (const float*)d_in[0];
    const float* wp  = (const float*)d_in[1];
    const float* bp  = (const float*)d_in[2];
    const float* wm  = (const float*)d_in[3];
    const float* bm  = (const float*)d_in[4];
    const float* wcv = (const float*)d_in[5];
    float* ws = (float*)d_ws;
    float* out = (float*)d_out;

    hipLaunchKernelGGL(k_pxt, dim3(1248), dim3(256), 0, stream, x, wp, bp, wm, bm, wcv, ws);
    hipLaunchKernelGGL(k_main, dim3(1024), dim3(256), 0, stream, ws, out);
}